// Round 6
// baseline (283.405 us; speedup 1.0000x reference)
//
#include <hip/hip_runtime.h>
#include <hip/hip_cooperative_groups.h>

namespace cg = cooperative_groups;

// Problem constants
#define EPSBN 1e-5f
#define CNT1 524288.0f   // B*N*K
#define CNT3 32768.0f    // B*N
#define NREP 16          // stats replicas (atomic spread)

typedef short v8s __attribute__((ext_vector_type(8)));
typedef float v16f __attribute__((ext_vector_type(16)));

__device__ __forceinline__ unsigned short f2bf(float f) {
  union { float f; unsigned u; } v; v.f = f;
  unsigned u = v.u;
  u += 0x7fffu + ((u >> 16) & 1u);   // RNE
  return (unsigned short)(u >> 16);
}
__device__ __forceinline__ unsigned pack2bf(float a, float b) {
  return (unsigned)f2bf(a) | ((unsigned)f2bf(b) << 16);
}
__device__ __forceinline__ float bflo(unsigned u) {
  union { unsigned u; float f; } v; v.u = u << 16; return v.f;
}
__device__ __forceinline__ float bfhi(unsigned u) {
  union { unsigned u; float f; } v; v.u = u & 0xffff0000u; return v.f;
}

// ===========================================================================
// Phase bodies (grid-stride over 512 work units; nb = gridDim.x)
// ===========================================================================

// Phase 0: y = W1*x (bf16) per point; zero stats.
__device__ __forceinline__ void phase0(
    int nb, const float* __restrict__ x, const float* __restrict__ W1f,
    unsigned short* __restrict__ y, float* __restrict__ stats, char* lds) {
  int t = threadIdx.x;
  for (int i = blockIdx.x * 256 + t; i < 3 * NREP * 128; i += nb * 256)
    stats[i] = 0.f;
  unsigned short* ldsX = (unsigned short*)lds;  // [point][ch] pad 72
  int lane = t & 63, w = t >> 6;
  int l31 = lane & 31, lh = lane >> 5;
  int ot = w & 1, ph = w >> 1;
  int o = ot * 32 + l31;
  v8s wfr[4];
#pragma unroll
  for (int ks = 0; ks < 4; ++ks) {
    const float* wrow = W1f + o * 64 + ks * 16 + lh * 8;
    float4 wa = *((const float4*)wrow);
    float4 wb = *((const float4*)(wrow + 4));
    unsigned* wu = (unsigned*)&wfr[ks];
    wu[0] = pack2bf(wa.x, wa.y); wu[1] = pack2bf(wa.z, wa.w);
    wu[2] = pack2bf(wb.x, wb.y); wu[3] = pack2bf(wb.z, wb.w);
  }
  for (int u = blockIdx.x; u < 512; u += nb) {
    int b = u >> 6, n0 = (u & 63) << 6;
#pragma unroll
    for (int i = 0; i < 16; ++i) {
      int c = w * 16 + i;
      ldsX[lane * 72 + c] = f2bf(x[(((size_t)(b * 64 + c)) << 12) + n0 + lane]);
    }
    __syncthreads();
    v16f acc;
#pragma unroll
    for (int i = 0; i < 16; ++i) acc[i] = 0.f;
#pragma unroll
    for (int ks = 0; ks < 4; ++ks) {
      v8s af = *((const v8s*)&ldsX[(ph * 32 + l31) * 72 + ks * 16 + lh * 8]);
      acc = __builtin_amdgcn_mfma_f32_32x32x16_bf16(af, wfr[ks], acc, 0, 0, 0);
    }
#pragma unroll
    for (int i = 0; i < 16; ++i) {
      int row = (i & 3) + ((i >> 2) << 3) + (lh << 2);
      int pt = (b << 12) + n0 + ph * 32 + row;
      y[pt * 64 + o] = f2bf(acc[i]);
    }
    __syncthreads();
  }
}

// Phase 1: stats1 = sum/sumsq of (y_j - y_i) over all edges.
__device__ __forceinline__ void phase1(
    int nb, const unsigned short* __restrict__ y, const int* __restrict__ idx,
    float* __restrict__ S1, float* bs, float* bq) {
  int t = threadIdx.x;
  if (t < 64) { bs[t] = 0.f; bq[t] = 0.f; }
  __syncthreads();
  int lane = t & 63, w = t >> 6;
  int ch = (lane & 7) << 3, eg = lane >> 3;
  float ss[8], sq[8];
#pragma unroll
  for (int k = 0; k < 8; ++k) { ss[k] = 0.f; sq[k] = 0.f; }
  for (int u = blockIdx.x; u < 512; u += nb) {
    int batch = u & 7, bi = u >> 3;
    int ebase = (batch << 16) + bi * 1024 + w * 256;
    for (int it = 0; it < 32; ++it) {
      int p = ebase + it * 8 + eg;
      int j = idx[p];
      int site = p >> 4;
      uint4 uj = *((const uint4*)(y + (((size_t)((batch << 12) + j)) << 6) + ch));
      uint4 ui = *((const uint4*)(y + (((size_t)site) << 6) + ch));
      const unsigned* aj = (const unsigned*)&uj;
      const unsigned* ai = (const unsigned*)&ui;
#pragma unroll
      for (int d = 0; d < 4; ++d) {
        float d0 = bflo(aj[d]) - bflo(ai[d]);
        float d1 = bfhi(aj[d]) - bfhi(ai[d]);
        ss[2 * d] += d0; sq[2 * d] += d0 * d0;
        ss[2 * d + 1] += d1; sq[2 * d + 1] += d1 * d1;
      }
    }
  }
#pragma unroll
  for (int k = 0; k < 8; ++k) {
    ss[k] += __shfl_xor(ss[k], 8);  sq[k] += __shfl_xor(sq[k], 8);
    ss[k] += __shfl_xor(ss[k], 16); sq[k] += __shfl_xor(sq[k], 16);
    ss[k] += __shfl_xor(ss[k], 32); sq[k] += __shfl_xor(sq[k], 32);
  }
  if (lane < 8) {
#pragma unroll
    for (int k = 0; k < 8; ++k) {
      atomicAdd(&bs[ch + k], ss[k]);
      atomicAdd(&bq[ch + k], sq[k]);
    }
  }
  __syncthreads();
  int rep = blockIdx.x & (NREP - 1);
  if (t < 64) atomicAdd(&S1[rep * 128 + t], bs[t]);
  else if (t < 128) atomicAdd(&S1[rep * 128 + t], bq[t - 64]);
}

// Phase 2: BN1 inline + GEMM2 + stats2 + per-site min/max.
__device__ __forceinline__ void phase2(
    int nb, const unsigned short* __restrict__ y, const int* __restrict__ idx,
    const float* __restrict__ W2f, const float* __restrict__ g1,
    const float* __restrict__ be1, const float* __restrict__ S1,
    unsigned short* __restrict__ mnb, unsigned short* __restrict__ mxb,
    float* __restrict__ S2, float* bs, float* bq, float* lA, float* lC) {
  int t = threadIdx.x;
  if (t < 64) {
    float s = 0.f, q = 0.f;
#pragma unroll
    for (int r = 0; r < NREP; ++r) { s += S1[r * 128 + t]; q += S1[r * 128 + 64 + t]; }
    float mean = s / CNT1;
    float var = q / CNT1 - mean * mean;
    float a = g1[t] * rsqrtf(var + EPSBN);
    lA[t] = a; lC[t] = be1[t] - mean * a;
    bs[t] = 0.f; bq[t] = 0.f;
  }
  __syncthreads();
  int lane = t & 63, w = t >> 6;
  int l31 = lane & 31, lh = lane >> 5;
  v8s w2[2][4];
#pragma unroll
  for (int s = 0; s < 2; ++s)
#pragma unroll
    for (int ks = 0; ks < 4; ++ks) {
      const float* wr = W2f + (s * 32 + l31) * 64 + ks * 16 + lh * 8;
      float4 wa = *((const float4*)wr);
      float4 wb = *((const float4*)(wr + 4));
      unsigned* wu = (unsigned*)&w2[s][ks];
      wu[0] = pack2bf(wa.x, wa.y); wu[1] = pack2bf(wa.z, wa.w);
      wu[2] = pack2bf(wb.x, wb.y); wu[3] = pack2bf(wb.z, wb.w);
    }
  float ss0 = 0.f, sq0 = 0.f, ss1 = 0.f, sq1 = 0.f;
  for (int u = blockIdx.x; u < 512; u += nb) {
    int batch = u & 7, bi = u >> 3;
    for (int it = 0; it < 8; ++it) {
      int tile = bi * 32 + w * 8 + it;  // 0..2047 within batch
      int p = (batch << 16) + (tile << 5) + l31;
      int j = idx[p];
      int site = p >> 4;
      const unsigned short* yj = y + (((size_t)((batch << 12) + j)) << 6) + lh * 8;
      const unsigned short* yi = y + (((size_t)site) << 6) + lh * 8;
      v16f b0, b1;
#pragma unroll
      for (int i = 0; i < 16; ++i) { b0[i] = 0.f; b1[i] = 0.f; }
#pragma unroll
      for (int ks = 0; ks < 4; ++ks) {
        uint4 uj = *((const uint4*)(yj + ks * 16));
        uint4 ui = *((const uint4*)(yi + ks * 16));
        float4 a0 = *((const float4*)&lA[ks * 16 + lh * 8]);
        float4 a1 = *((const float4*)&lA[ks * 16 + lh * 8 + 4]);
        float4 c0 = *((const float4*)&lC[ks * 16 + lh * 8]);
        float4 c1 = *((const float4*)&lC[ks * 16 + lh * 8 + 4]);
        float av[8] = {a0.x, a0.y, a0.z, a0.w, a1.x, a1.y, a1.z, a1.w};
        float cv[8] = {c0.x, c0.y, c0.z, c0.w, c1.x, c1.y, c1.z, c1.w};
        const unsigned* jw = (const unsigned*)&uj;
        const unsigned* iw = (const unsigned*)&ui;
        v8s af; unsigned* au = (unsigned*)&af;
#pragma unroll
        for (int d = 0; d < 4; ++d) {
          float e0 = fmaxf((bflo(jw[d]) - bflo(iw[d])) * av[2 * d] + cv[2 * d], 0.f);
          float e1 = fmaxf((bfhi(jw[d]) - bfhi(iw[d])) * av[2 * d + 1] + cv[2 * d + 1], 0.f);
          au[d] = pack2bf(e0, e1);
        }
        b0 = __builtin_amdgcn_mfma_f32_32x32x16_bf16(af, w2[0][ks], b0, 0, 0, 0);
        b1 = __builtin_amdgcn_mfma_f32_32x32x16_bf16(af, w2[1][ks], b1, 0, 0, 0);
      }
      float mx00 = b0[0], mn00 = b0[0], mx01 = b0[8], mn01 = b0[8];
      float mx10 = b1[0], mn10 = b1[0], mx11 = b1[8], mn11 = b1[8];
#pragma unroll
      for (int i = 0; i < 16; ++i) {
        ss0 += b0[i]; sq0 += b0[i] * b0[i];
        ss1 += b1[i]; sq1 += b1[i] * b1[i];
      }
#pragma unroll
      for (int i = 1; i < 8; ++i) {
        mx00 = fmaxf(mx00, b0[i]);     mn00 = fminf(mn00, b0[i]);
        mx01 = fmaxf(mx01, b0[8 + i]); mn01 = fminf(mn01, b0[8 + i]);
        mx10 = fmaxf(mx10, b1[i]);     mn10 = fminf(mn10, b1[i]);
        mx11 = fmaxf(mx11, b1[8 + i]); mn11 = fminf(mn11, b1[8 + i]);
      }
      mx00 = fmaxf(mx00, __shfl_xor(mx00, 32)); mn00 = fminf(mn00, __shfl_xor(mn00, 32));
      mx01 = fmaxf(mx01, __shfl_xor(mx01, 32)); mn01 = fminf(mn01, __shfl_xor(mn01, 32));
      mx10 = fmaxf(mx10, __shfl_xor(mx10, 32)); mn10 = fminf(mn10, __shfl_xor(mn10, 32));
      mx11 = fmaxf(mx11, __shfl_xor(mx11, 32)); mn11 = fminf(mn11, __shfl_xor(mn11, 32));
      int s2 = (batch << 12) + (tile << 1);
      if (lh == 0) {
        mnb[(size_t)(s2 + 0) * 64 + l31] = f2bf(mn00);
        mnb[(size_t)(s2 + 1) * 64 + l31] = f2bf(mn01);
        mnb[(size_t)(s2 + 0) * 64 + 32 + l31] = f2bf(mn10);
        mnb[(size_t)(s2 + 1) * 64 + 32 + l31] = f2bf(mn11);
      } else {
        mxb[(size_t)(s2 + 0) * 64 + l31] = f2bf(mx00);
        mxb[(size_t)(s2 + 1) * 64 + l31] = f2bf(mx01);
        mxb[(size_t)(s2 + 0) * 64 + 32 + l31] = f2bf(mx10);
        mxb[(size_t)(s2 + 1) * 64 + 32 + l31] = f2bf(mx11);
      }
    }
  }
  ss0 += __shfl_xor(ss0, 32); sq0 += __shfl_xor(sq0, 32);
  ss1 += __shfl_xor(ss1, 32); sq1 += __shfl_xor(sq1, 32);
  if (lh == 0) {
    atomicAdd(&bs[l31], ss0); atomicAdd(&bq[l31], sq0);
    atomicAdd(&bs[32 + l31], ss1); atomicAdd(&bq[32 + l31], sq1);
  }
  __syncthreads();
  int rep = blockIdx.x & (NREP - 1);
  if (t < 64) atomicAdd(&S2[rep * 128 + t], bs[t]);
  else if (t < 128) atomicAdd(&S2[rep * 128 + t], bq[t - 64]);
}

// Phase 3: BN2 sign-select + GEMM3 -> h3, stats3.
__device__ __forceinline__ void phase3(
    int nb, const float* __restrict__ W3f, const unsigned short* __restrict__ mnb,
    const unsigned short* __restrict__ mxb, const float* __restrict__ g2,
    const float* __restrict__ be2, const float* __restrict__ S2,
    float* __restrict__ h3, float* __restrict__ S3,
    float* bs, float* bq, float* lA, float* lC, char* lds) {
  uint4* ldsA = (uint4*)lds;  // 64 rows x 9 uint4
  int t = threadIdx.x;
  if (t < 64) {
    float s = 0.f, q = 0.f;
#pragma unroll
    for (int r = 0; r < NREP; ++r) { s += S2[r * 128 + t]; q += S2[r * 128 + 64 + t]; }
    float mean = s / CNT1;
    float var = q / CNT1 - mean * mean;
    float a = g2[t] * rsqrtf(var + EPSBN);
    lA[t] = a; lC[t] = be2[t] - mean * a;
    bs[t] = 0.f; bq[t] = 0.f;
  }
  __syncthreads();
  int lane = t & 63, w = t >> 6;
  int l31 = lane & 31, lh = lane >> 5;
  int rb = w & 1, ctile = w >> 1;
  int o = ctile * 32 + l31;
  v8s wf[4];
#pragma unroll
  for (int ks = 0; ks < 4; ++ks) {
    const float* wr = W3f + o * 64 + ks * 16 + lh * 8;
    float4 wa = *((const float4*)wr);
    float4 wb = *((const float4*)(wr + 4));
    unsigned* wu = (unsigned*)&wf[ks];
    wu[0] = pack2bf(wa.x, wa.y); wu[1] = pack2bf(wa.z, wa.w);
    wu[2] = pack2bf(wb.x, wb.y); wu[3] = pack2bf(wb.z, wb.w);
  }
  int r = t >> 2, q = t & 3;
  int arow = rb * 32 + l31;
  float ssum = 0.f, ssq = 0.f;
  for (int u = blockIdx.x; u < 512; u += nb) {
    int s0 = u << 6;
    {
      int site = s0 + r;
      const uint4* mnp = (const uint4*)(mnb + (size_t)site * 64 + q * 16);
      const uint4* mxp = (const uint4*)(mxb + (size_t)site * 64 + q * 16);
      uint4 m0 = mnp[0], m1 = mnp[1], x0 = mxp[0], x1 = mxp[1];
      uint4 ch2[2];
      unsigned* cu = (unsigned*)ch2;
#pragma unroll
      for (int d = 0; d < 8; ++d) {
        unsigned md = (d < 4) ? ((const unsigned*)&m0)[d] : ((const unsigned*)&m1)[d - 4];
        unsigned xd = (d < 4) ? ((const unsigned*)&x0)[d] : ((const unsigned*)&x1)[d - 4];
        int c = q * 16 + 2 * d;
        float a0 = lA[c], a1 = lA[c + 1];
        float s0v = (a0 > 0.f) ? bflo(xd) : bflo(md);
        float s1v = (a1 > 0.f) ? bfhi(xd) : bfhi(md);
        float v0 = fmaxf(a0 * s0v + lC[c], 0.f);
        float v1 = fmaxf(a1 * s1v + lC[c + 1], 0.f);
        cu[d] = pack2bf(v0, v1);
      }
      ldsA[r * 9 + q * 2 + 0] = ch2[0];
      ldsA[r * 9 + q * 2 + 1] = ch2[1];
    }
    __syncthreads();
    v16f acc;
#pragma unroll
    for (int i = 0; i < 16; ++i) acc[i] = 0.f;
#pragma unroll
    for (int ks = 0; ks < 4; ++ks) {
      v8s a = *((const v8s*)&ldsA[arow * 9 + ks * 2 + lh]);
      acc = __builtin_amdgcn_mfma_f32_32x32x16_bf16(a, wf[ks], acc, 0, 0, 0);
    }
#pragma unroll
    for (int i = 0; i < 16; ++i) {
      float vv = acc[i];
      ssum += vv; ssq += vv * vv;
      int row = (i & 3) + ((i >> 2) << 3) + (lh << 2);
      h3[(((size_t)(s0 + rb * 32 + row)) << 6) + o] = vv;
    }
    __syncthreads();
  }
  ssum += __shfl_xor(ssum, 32);
  ssq += __shfl_xor(ssq, 32);
  if (lh == 0) { atomicAdd(&bs[o], ssum); atomicAdd(&bq[o], ssq); }
  __syncthreads();
  int rep = blockIdx.x & (NREP - 1);
  if (t < 64) atomicAdd(&S3[rep * 128 + t], bs[t]);
  else if (t < 128) atomicAdd(&S3[rep * 128 + t], bq[t - 64]);
}

// Phase 4: BN3+ReLU + transpose -> out.
__device__ __forceinline__ void phase4(
    int nb, const float* __restrict__ h3, const float* __restrict__ g3,
    const float* __restrict__ be3, const float* __restrict__ S3,
    float* __restrict__ out, float* lA, float* lC, char* lds) {
  float* tile = (float*)lds;  // [64][65]
  int t = threadIdx.x;
  if (t < 64) {
    float s = 0.f, q = 0.f;
#pragma unroll
    for (int r = 0; r < NREP; ++r) { s += S3[r * 128 + t]; q += S3[r * 128 + 64 + t]; }
    float mean = s / CNT3;
    float var = q / CNT3 - mean * mean;
    float a = g3[t] * rsqrtf(var + EPSBN);
    lA[t] = a; lC[t] = be3[t] - mean * a;
  }
  __syncthreads();
  int r = t >> 2, q = t & 3;
  for (int u = blockIdx.x; u < 512; u += nb) {
    int b = u >> 6, n0 = (u & 63) << 6;
    const float4* hp = (const float4*)(h3 + (((size_t)((b << 12) + n0 + r)) << 6)) + q * 4;
#pragma unroll
    for (int ii = 0; ii < 4; ++ii) {
      float4 v = hp[ii];
      int c = q * 16 + ii * 4;
      tile[(c + 0) * 65 + r] = fmaxf(v.x * lA[c + 0] + lC[c + 0], 0.f);
      tile[(c + 1) * 65 + r] = fmaxf(v.y * lA[c + 1] + lC[c + 1], 0.f);
      tile[(c + 2) * 65 + r] = fmaxf(v.z * lA[c + 2] + lC[c + 2], 0.f);
      tile[(c + 3) * 65 + r] = fmaxf(v.w * lA[c + 3] + lC[c + 3], 0.f);
    }
    __syncthreads();
    int oo = t >> 2, seg = t & 3;
    float4* dst = (float4*)(out + (((size_t)(b * 64 + oo)) << 12) + n0 + seg * 16);
#pragma unroll
    for (int ii = 0; ii < 4; ++ii) {
      float4 v;
      v.x = tile[oo * 65 + seg * 16 + ii * 4 + 0];
      v.y = tile[oo * 65 + seg * 16 + ii * 4 + 1];
      v.z = tile[oo * 65 + seg * 16 + ii * 4 + 2];
      v.w = tile[oo * 65 + seg * 16 + ii * 4 + 3];
      dst[ii] = v;
    }
    __syncthreads();
  }
}

// ===========================================================================
// Fused cooperative kernel
// ===========================================================================
__global__ __launch_bounds__(256, 2) void fused_all(
    const float* x, const int* idx, const float* W1f, const float* W2f,
    const float* W3f, const float* g1, const float* be1, const float* g2,
    const float* be2, const float* g3, const float* be3,
    unsigned short* y, unsigned short* mnb, unsigned short* mxb,
    float* h3, float* stats, float* out) {
  cg::grid_group grid = cg::this_grid();
  __shared__ __align__(16) char lds[16640];
  __shared__ float bs[64], bq[64];
  __shared__ __align__(16) float lA[64];
  __shared__ __align__(16) float lC[64];
  int nb = gridDim.x;
  float* S1 = stats;
  float* S2 = stats + NREP * 128;
  float* S3 = stats + 2 * NREP * 128;
  phase0(nb, x, W1f, y, stats, lds);
  grid.sync();
  phase1(nb, y, idx, S1, bs, bq);
  grid.sync();
  phase2(nb, y, idx, W2f, g1, be1, S1, mnb, mxb, S2, bs, bq, lA, lC);
  grid.sync();
  phase3(nb, W3f, mnb, mxb, g2, be2, S2, h3, S3, bs, bq, lA, lC, lds);
  grid.sync();
  phase4(nb, h3, g3, be3, S3, out, lA, lC, lds);
}

// ===========================================================================
// Fallback: 5 ordinary kernels (same phase bodies; kernel boundaries = sync)
// ===========================================================================
__global__ __launch_bounds__(256) void k0(const float* x, const float* W1f,
                                          unsigned short* y, float* stats) {
  __shared__ __align__(16) char lds[9216];
  phase0(gridDim.x, x, W1f, y, stats, lds);
}
__global__ __launch_bounds__(256) void k1(const unsigned short* y, const int* idx,
                                          float* S1) {
  __shared__ float bs[64], bq[64];
  phase1(gridDim.x, y, idx, S1, bs, bq);
}
__global__ __launch_bounds__(256) void k2(const unsigned short* y, const int* idx,
                                          const float* W2f, const float* g1,
                                          const float* be1, const float* S1,
                                          unsigned short* mnb, unsigned short* mxb,
                                          float* S2) {
  __shared__ float bs[64], bq[64];
  __shared__ __align__(16) float lA[64];
  __shared__ __align__(16) float lC[64];
  phase2(gridDim.x, y, idx, W2f, g1, be1, S1, mnb, mxb, S2, bs, bq, lA, lC);
}
__global__ __launch_bounds__(256) void k3(const float* W3f, const unsigned short* mnb,
                                          const unsigned short* mxb, const float* g2,
                                          const float* be2, const float* S2,
                                          float* h3, float* S3) {
  __shared__ __align__(16) char lds[9216];
  __shared__ float bs[64], bq[64];
  __shared__ __align__(16) float lA[64];
  __shared__ __align__(16) float lC[64];
  phase3(gridDim.x, W3f, mnb, mxb, g2, be2, S2, h3, S3, bs, bq, lA, lC, lds);
}
__global__ __launch_bounds__(256) void k4(const float* h3, const float* g3,
                                          const float* be3, const float* S3,
                                          float* out) {
  __shared__ __align__(16) char lds[16640];
  __shared__ __align__(16) float lA[64];
  __shared__ __align__(16) float lC[64];
  phase4(gridDim.x, h3, g3, be3, S3, out, lA, lC, lds);
}

// ===========================================================================
extern "C" void kernel_launch(void* const* d_in, const int* in_sizes, int n_in,
                              void* d_out, int out_size, void* d_ws, size_t ws_size,
                              hipStream_t stream) {
  const float* x = (const float*)d_in[0];
  const int* idx = (const int*)d_in[1];
  const float* W1 = (const float*)d_in[2];
  const float* g1 = (const float*)d_in[4];
  const float* be1 = (const float*)d_in[5];
  const float* W2 = (const float*)d_in[6];
  const float* g2 = (const float*)d_in[8];
  const float* be2 = (const float*)d_in[9];
  const float* W3 = (const float*)d_in[10];
  const float* g3 = (const float*)d_in[12];
  const float* be3 = (const float*)d_in[13];
  float* out = (float*)d_out;

  char* ws = (char*)d_ws;
  unsigned short* y   = (unsigned short*)ws;                 // 4 MB
  unsigned short* mnb = (unsigned short*)(ws + (4u << 20));  // 4 MB
  unsigned short* mxb = (unsigned short*)(ws + (8u << 20));  // 4 MB
  float* h3           = (float*)(ws + (12u << 20));          // 8 MB
  float* stats        = (float*)(ws + (20u << 20));          // 3*NREP*128 floats

  // Size cooperative grid from the runtime's own occupancy model.
  bool coop_ok = false;
  int perCU = 0;
  hipError_t oe = hipOccupancyMaxActiveBlocksPerMultiprocessor(
      &perCU, (const void*)fused_all, 256, 0);
  if (oe == hipSuccess && perCU >= 1) {
    int dev = 0;
    (void)hipGetDevice(&dev);
    hipDeviceProp_t prop;
    hipError_t pe = hipGetDeviceProperties(&prop, dev);
    int cus = (pe == hipSuccess) ? prop.multiProcessorCount : 256;
    long grid = (long)perCU * (long)cus;
    if (grid > 512) grid = 512;
    if (grid >= 64) {
      void* args[] = {(void*)&x, (void*)&idx, (void*)&W1, (void*)&W2, (void*)&W3,
                      (void*)&g1, (void*)&be1, (void*)&g2, (void*)&be2,
                      (void*)&g3, (void*)&be3,
                      (void*)&y, (void*)&mnb, (void*)&mxb, (void*)&h3,
                      (void*)&stats, (void*)&out};
      hipError_t le = hipLaunchCooperativeKernel((const void*)fused_all,
                                                 dim3((unsigned)grid), dim3(256),
                                                 args, 0, stream);
      coop_ok = (le == hipSuccess);
      if (!coop_ok) (void)hipGetLastError();  // clear sticky error
    }
  } else {
    (void)hipGetLastError();
  }

  if (!coop_ok) {
    k0<<<512, 256, 0, stream>>>(x, W1, y, stats);
    k1<<<512, 256, 0, stream>>>(y, idx, stats);
    k2<<<512, 256, 0, stream>>>(y, idx, W2, g1, be1, stats, mnb, mxb,
                                stats + NREP * 128);
    k3<<<512, 256, 0, stream>>>(W3, mnb, mxb, g2, be2, stats + NREP * 128,
                                h3, stats + 2 * NREP * 128);
    k4<<<512, 256, 0, stream>>>(h3, g3, be3, stats + 2 * NREP * 128, out);
  }
}

// Round 7
// 141.504 us; speedup vs baseline: 2.0028x; 2.0028x over previous
//
#include <hip/hip_runtime.h>

// Problem constants
#define EPSBN 1e-5f
#define CNT1 524288.0f   // B*N*K
#define CNT3 32768.0f    // B*N
#define NREP 16          // stats replicas (atomic spread)

typedef short v8s __attribute__((ext_vector_type(8)));
typedef float v16f __attribute__((ext_vector_type(16)));

__device__ __forceinline__ unsigned short f2bf(float f) {
  union { float f; unsigned u; } v; v.f = f;
  unsigned u = v.u;
  u += 0x7fffu + ((u >> 16) & 1u);   // RNE
  return (unsigned short)(u >> 16);
}
__device__ __forceinline__ unsigned pack2bf(float a, float b) {
  return (unsigned)f2bf(a) | ((unsigned)f2bf(b) << 16);
}
__device__ __forceinline__ float bflo(unsigned u) {
  union { unsigned u; float f; } v; v.u = u << 16; return v.f;
}
__device__ __forceinline__ float bfhi(unsigned u) {
  union { unsigned u; float f; } v; v.u = u & 0xffff0000u; return v.f;
}

// ---------------------------------------------------------------------------
// k0: y = W1*x (bf16, (B*N,64)); zero stats. 512 blocks.
// Block u -> batch u&7 (XCD-pinned, matches consumers), points (u>>3)*64.
// ---------------------------------------------------------------------------
__global__ __launch_bounds__(256) void k0_prep(
    const float* __restrict__ x, const float* __restrict__ W1f,
    unsigned short* __restrict__ y, float* __restrict__ stats) {
  __shared__ unsigned short ldsX[64 * 72];  // [point][ch], pad 72
  int blk = blockIdx.x, t = threadIdx.x;
  if (blk < 24) stats[blk * 256 + t] = 0.f;
  int b = blk & 7, n0 = (blk >> 3) << 6;
  int lane = t & 63, w = t >> 6;
#pragma unroll
  for (int i = 0; i < 16; ++i) {
    int c = w * 16 + i;
    ldsX[lane * 72 + c] = f2bf(x[(((size_t)(b * 64 + c)) << 12) + n0 + lane]);
  }
  __syncthreads();
  int l31 = lane & 31, lh = lane >> 5;
  int ot = w & 1, ph = w >> 1;
  int o = ot * 32 + l31;
  v16f acc;
#pragma unroll
  for (int i = 0; i < 16; ++i) acc[i] = 0.f;
#pragma unroll
  for (int ks = 0; ks < 4; ++ks) {
    const float* wrow = W1f + o * 64 + ks * 16 + lh * 8;
    float4 wa = *((const float4*)wrow);
    float4 wb = *((const float4*)(wrow + 4));
    v8s wf; unsigned* wu = (unsigned*)&wf;
    wu[0] = pack2bf(wa.x, wa.y); wu[1] = pack2bf(wa.z, wa.w);
    wu[2] = pack2bf(wb.x, wb.y); wu[3] = pack2bf(wb.z, wb.w);
    v8s af = *((const v8s*)&ldsX[(ph * 32 + l31) * 72 + ks * 16 + lh * 8]);
    acc = __builtin_amdgcn_mfma_f32_32x32x16_bf16(af, wf, acc, 0, 0, 0);
  }
#pragma unroll
  for (int i = 0; i < 16; ++i) {
    int row = (i & 3) + ((i >> 2) << 3) + (lh << 2);
    int pt = (b << 12) + n0 + ph * 32 + row;
    y[pt * 64 + o] = f2bf(acc[i]);
  }
}

// ---------------------------------------------------------------------------
// k1: stats1 = sum/sumsq of (y_j - y_i) over all edges. 1024 blocks.
// ---------------------------------------------------------------------------
__global__ __launch_bounds__(256) void k1_stats(
    const unsigned short* __restrict__ y, const int* __restrict__ idx,
    float* __restrict__ S1) {
  __shared__ float bs[64], bq[64];
  int t = threadIdx.x;
  if (t < 64) { bs[t] = 0.f; bq[t] = 0.f; }
  __syncthreads();
  int blk = blockIdx.x;
  int batch = blk & 7, bi = blk >> 3;       // bi 0..127
  int w = t >> 6, lane = t & 63;
  int ch = (lane & 7) << 3, eg = lane >> 3;
  int ebase = (batch << 16) + bi * 512 + w * 128;
  float ss[8], sq[8];
#pragma unroll
  for (int k = 0; k < 8; ++k) { ss[k] = 0.f; sq[k] = 0.f; }
#pragma unroll 2
  for (int it = 0; it < 16; ++it) {
    int p = ebase + it * 8 + eg;
    int j = idx[p];
    int site = p >> 4;
    uint4 uj = *((const uint4*)(y + (((size_t)((batch << 12) + j)) << 6) + ch));
    uint4 ui = *((const uint4*)(y + (((size_t)site) << 6) + ch));
    const unsigned* aj = (const unsigned*)&uj;
    const unsigned* ai = (const unsigned*)&ui;
#pragma unroll
    for (int d = 0; d < 4; ++d) {
      float d0 = bflo(aj[d]) - bflo(ai[d]);
      float d1 = bfhi(aj[d]) - bfhi(ai[d]);
      ss[2 * d] += d0; sq[2 * d] += d0 * d0;
      ss[2 * d + 1] += d1; sq[2 * d + 1] += d1 * d1;
    }
  }
#pragma unroll
  for (int k = 0; k < 8; ++k) {
    ss[k] += __shfl_xor(ss[k], 8);  sq[k] += __shfl_xor(sq[k], 8);
    ss[k] += __shfl_xor(ss[k], 16); sq[k] += __shfl_xor(sq[k], 16);
    ss[k] += __shfl_xor(ss[k], 32); sq[k] += __shfl_xor(sq[k], 32);
  }
  if (lane < 8) {
#pragma unroll
    for (int k = 0; k < 8; ++k) {
      atomicAdd(&bs[ch + k], ss[k]);
      atomicAdd(&bq[ch + k], sq[k]);
    }
  }
  __syncthreads();
  int rep = (blk >> 3) & (NREP - 1);
  if (t < 64) atomicAdd(&S1[rep * 128 + t], bs[t]);
  else if (t < 128) atomicAdd(&S1[rep * 128 + t], bq[t - 64]);
}

// ---------------------------------------------------------------------------
// k2: edge = relu(a1*(y_j - y_i) + c1) as MFMA A-frags, GEMM2, stats2,
// per-site min/max -> mnb/mxb (bf16). 1024 blocks x 4 waves x 4 tiles.
// ---------------------------------------------------------------------------
__global__ __launch_bounds__(256) void k2_main(
    const unsigned short* __restrict__ y, const int* __restrict__ idx,
    const float* __restrict__ W2f,
    const float* __restrict__ g1, const float* __restrict__ be1,
    const float* __restrict__ S1,
    unsigned short* __restrict__ mnb, unsigned short* __restrict__ mxb,
    float* __restrict__ S2) {
  __shared__ float bs[64], bq[64];
  __shared__ __align__(16) float lA[64];
  __shared__ __align__(16) float lC[64];
  int t = threadIdx.x;
  if (t < 64) {
    bs[t] = 0.f; bq[t] = 0.f;
    float s = 0.f, q = 0.f;
#pragma unroll
    for (int r = 0; r < NREP; ++r) { s += S1[r * 128 + t]; q += S1[r * 128 + 64 + t]; }
    float mean = s / CNT1;
    float var = q / CNT1 - mean * mean;
    float a = g1[t] * rsqrtf(var + EPSBN);
    lA[t] = a; lC[t] = be1[t] - mean * a;
  }
  __syncthreads();
  int blk = blockIdx.x;
  int batch = blk & 7, bi = blk >> 3;   // bi 0..127
  int w = t >> 6, lane = t & 63;
  int l31 = lane & 31, lh = lane >> 5;
  v8s w2[2][4];
#pragma unroll
  for (int s = 0; s < 2; ++s)
#pragma unroll
    for (int ks = 0; ks < 4; ++ks) {
      const float* wr = W2f + (s * 32 + l31) * 64 + ks * 16 + lh * 8;
      float4 wa = *((const float4*)wr);
      float4 wb = *((const float4*)(wr + 4));
      unsigned* wu = (unsigned*)&w2[s][ks];
      wu[0] = pack2bf(wa.x, wa.y); wu[1] = pack2bf(wa.z, wa.w);
      wu[2] = pack2bf(wb.x, wb.y); wu[3] = pack2bf(wb.z, wb.w);
    }
  float ss0 = 0.f, sq0 = 0.f, ss1 = 0.f, sq1 = 0.f;
#pragma unroll 2
  for (int it = 0; it < 4; ++it) {
    int tile = bi * 16 + w * 4 + it;            // 0..2047 within batch
    int p = (batch << 16) + (tile << 5) + l31;
    int j = idx[p];
    int site = p >> 4;
    const unsigned short* yj = y + (((size_t)((batch << 12) + j)) << 6) + lh * 8;
    const unsigned short* yi = y + (((size_t)site) << 6) + lh * 8;
    v16f b0, b1;
#pragma unroll
    for (int i = 0; i < 16; ++i) { b0[i] = 0.f; b1[i] = 0.f; }
#pragma unroll
    for (int ks = 0; ks < 4; ++ks) {
      uint4 uj = *((const uint4*)(yj + ks * 16));
      uint4 ui = *((const uint4*)(yi + ks * 16));
      float4 a0 = *((const float4*)&lA[ks * 16 + lh * 8]);
      float4 a1 = *((const float4*)&lA[ks * 16 + lh * 8 + 4]);
      float4 c0 = *((const float4*)&lC[ks * 16 + lh * 8]);
      float4 c1 = *((const float4*)&lC[ks * 16 + lh * 8 + 4]);
      float av[8] = {a0.x, a0.y, a0.z, a0.w, a1.x, a1.y, a1.z, a1.w};
      float cv[8] = {c0.x, c0.y, c0.z, c0.w, c1.x, c1.y, c1.z, c1.w};
      const unsigned* jw = (const unsigned*)&uj;
      const unsigned* iw = (const unsigned*)&ui;
      v8s af; unsigned* au = (unsigned*)&af;
#pragma unroll
      for (int d = 0; d < 4; ++d) {
        float e0 = fmaxf((bflo(jw[d]) - bflo(iw[d])) * av[2 * d] + cv[2 * d], 0.f);
        float e1 = fmaxf((bfhi(jw[d]) - bfhi(iw[d])) * av[2 * d + 1] + cv[2 * d + 1], 0.f);
        au[d] = pack2bf(e0, e1);
      }
      b0 = __builtin_amdgcn_mfma_f32_32x32x16_bf16(af, w2[0][ks], b0, 0, 0, 0);
      b1 = __builtin_amdgcn_mfma_f32_32x32x16_bf16(af, w2[1][ks], b1, 0, 0, 0);
    }
    float mx00 = b0[0], mn00 = b0[0], mx01 = b0[8], mn01 = b0[8];
    float mx10 = b1[0], mn10 = b1[0], mx11 = b1[8], mn11 = b1[8];
#pragma unroll
    for (int i = 0; i < 16; ++i) {
      ss0 += b0[i]; sq0 += b0[i] * b0[i];
      ss1 += b1[i]; sq1 += b1[i] * b1[i];
    }
#pragma unroll
    for (int i = 1; i < 8; ++i) {
      mx00 = fmaxf(mx00, b0[i]);     mn00 = fminf(mn00, b0[i]);
      mx01 = fmaxf(mx01, b0[8 + i]); mn01 = fminf(mn01, b0[8 + i]);
      mx10 = fmaxf(mx10, b1[i]);     mn10 = fminf(mn10, b1[i]);
      mx11 = fmaxf(mx11, b1[8 + i]); mn11 = fminf(mn11, b1[8 + i]);
    }
    mx00 = fmaxf(mx00, __shfl_xor(mx00, 32)); mn00 = fminf(mn00, __shfl_xor(mn00, 32));
    mx01 = fmaxf(mx01, __shfl_xor(mx01, 32)); mn01 = fminf(mn01, __shfl_xor(mn01, 32));
    mx10 = fmaxf(mx10, __shfl_xor(mx10, 32)); mn10 = fminf(mn10, __shfl_xor(mn10, 32));
    mx11 = fmaxf(mx11, __shfl_xor(mx11, 32)); mn11 = fminf(mn11, __shfl_xor(mn11, 32));
    int s2 = (batch << 12) + (tile << 1);
    if (lh == 0) {
      mnb[(size_t)(s2 + 0) * 64 + l31] = f2bf(mn00);
      mnb[(size_t)(s2 + 1) * 64 + l31] = f2bf(mn01);
      mnb[(size_t)(s2 + 0) * 64 + 32 + l31] = f2bf(mn10);
      mnb[(size_t)(s2 + 1) * 64 + 32 + l31] = f2bf(mn11);
    } else {
      mxb[(size_t)(s2 + 0) * 64 + l31] = f2bf(mx00);
      mxb[(size_t)(s2 + 1) * 64 + l31] = f2bf(mx01);
      mxb[(size_t)(s2 + 0) * 64 + 32 + l31] = f2bf(mx10);
      mxb[(size_t)(s2 + 1) * 64 + 32 + l31] = f2bf(mx11);
    }
  }
  ss0 += __shfl_xor(ss0, 32); sq0 += __shfl_xor(sq0, 32);
  ss1 += __shfl_xor(ss1, 32); sq1 += __shfl_xor(sq1, 32);
  if (lh == 0) {
    atomicAdd(&bs[l31], ss0); atomicAdd(&bq[l31], sq0);
    atomicAdd(&bs[32 + l31], ss1); atomicAdd(&bq[32 + l31], sq1);
  }
  __syncthreads();
  int rep = blk & (NREP - 1);
  if (t < 64) atomicAdd(&S2[rep * 128 + t], bs[t]);
  else if (t < 128) atomicAdd(&S2[rep * 128 + t], bq[t - 64]);
}

// ---------------------------------------------------------------------------
// k3: BN2 sign-select on bf16 min/max, ReLU, GEMM3 -> h3 fp32, stats3.
// 512 blocks; block u -> batch u&7 (matches k2's mnb/mxb XCD pinning).
// ---------------------------------------------------------------------------
__global__ __launch_bounds__(256, 2) void k3_gemm3(
    const float* __restrict__ W3f,
    const unsigned short* __restrict__ mnb, const unsigned short* __restrict__ mxb,
    const float* __restrict__ g2, const float* __restrict__ be2,
    const float* __restrict__ S2, float* __restrict__ h3, float* __restrict__ S3) {
  __shared__ uint4 ldsA[64 * 9];
  __shared__ float bs[64], bq[64], lA[64], lC[64];
  int t = threadIdx.x;
  if (t < 64) {
    bs[t] = 0.f; bq[t] = 0.f;
    float s = 0.f, q = 0.f;
#pragma unroll
    for (int r = 0; r < NREP; ++r) { s += S2[r * 128 + t]; q += S2[r * 128 + 64 + t]; }
    float mean = s / CNT1;
    float var = q / CNT1 - mean * mean;
    float a = g2[t] * rsqrtf(var + EPSBN);
    lA[t] = a; lC[t] = be2[t] - mean * a;
  }
  __syncthreads();
  int lane = t & 63, wid = t >> 6;
  int rb = wid & 1, ctile = wid >> 1;
  int l31 = lane & 31, lh = lane >> 5;
  int o = ctile * 32 + l31;
  v8s wf[4];
#pragma unroll
  for (int ks = 0; ks < 4; ++ks) {
    const float* wr = W3f + o * 64 + ks * 16 + lh * 8;
    float4 wa = *((const float4*)wr);
    float4 wb = *((const float4*)(wr + 4));
    unsigned* wu = (unsigned*)&wf[ks];
    wu[0] = pack2bf(wa.x, wa.y); wu[1] = pack2bf(wa.z, wa.w);
    wu[2] = pack2bf(wb.x, wb.y); wu[3] = pack2bf(wb.z, wb.w);
  }
  int r = t >> 2, q = t & 3;
  int arow = rb * 32 + l31;
  int blk = blockIdx.x;
  int s0 = ((blk & 7) << 12) + ((blk >> 3) << 6);
  {
    int site = s0 + r;
    const uint4* mnp = (const uint4*)(mnb + (size_t)site * 64 + q * 16);
    const uint4* mxp = (const uint4*)(mxb + (size_t)site * 64 + q * 16);
    uint4 m0 = mnp[0], m1 = mnp[1], x0 = mxp[0], x1 = mxp[1];
    uint4 ch2[2];
    unsigned* cu = (unsigned*)ch2;
#pragma unroll
    for (int d = 0; d < 8; ++d) {
      unsigned md = (d < 4) ? ((const unsigned*)&m0)[d] : ((const unsigned*)&m1)[d - 4];
      unsigned xd = (d < 4) ? ((const unsigned*)&x0)[d] : ((const unsigned*)&x1)[d - 4];
      int c = q * 16 + 2 * d;
      float a0 = lA[c], a1 = lA[c + 1];
      float s0v = (a0 > 0.f) ? bflo(xd) : bflo(md);
      float s1v = (a1 > 0.f) ? bfhi(xd) : bfhi(md);
      float v0 = fmaxf(a0 * s0v + lC[c], 0.f);
      float v1 = fmaxf(a1 * s1v + lC[c + 1], 0.f);
      cu[d] = pack2bf(v0, v1);
    }
    ldsA[r * 9 + q * 2 + 0] = ch2[0];
    ldsA[r * 9 + q * 2 + 1] = ch2[1];
  }
  __syncthreads();
  v16f acc;
#pragma unroll
  for (int i = 0; i < 16; ++i) acc[i] = 0.f;
#pragma unroll
  for (int ks = 0; ks < 4; ++ks) {
    v8s a = *((const v8s*)&ldsA[arow * 9 + ks * 2 + lh]);
    acc = __builtin_amdgcn_mfma_f32_32x32x16_bf16(a, wf[ks], acc, 0, 0, 0);
  }
  float ssum = 0.f, ssq = 0.f;
#pragma unroll
  for (int i = 0; i < 16; ++i) {
    float vv = acc[i];
    ssum += vv; ssq += vv * vv;
    int row = (i & 3) + ((i >> 2) << 3) + (lh << 2);
    h3[(((size_t)(s0 + rb * 32 + row)) << 6) + o] = vv;
  }
  ssum += __shfl_xor(ssum, 32);
  ssq += __shfl_xor(ssq, 32);
  if (lh == 0) { atomicAdd(&bs[o], ssum); atomicAdd(&bq[o], ssq); }
  __syncthreads();
  int rep = blk & (NREP - 1);
  if (t < 64) atomicAdd(&S3[rep * 128 + t], bs[t]);
  else if (t < 128) atomicAdd(&S3[rep * 128 + t], bq[t - 64]);
}

// ---------------------------------------------------------------------------
// k4: BN3+ReLU, transpose (B,N,E)->(B,E,N), write out. 512 blocks.
// ---------------------------------------------------------------------------
__global__ void k4_out(const float* __restrict__ h3,
                       const float* __restrict__ g3, const float* __restrict__ be3,
                       float* __restrict__ out, const float* __restrict__ S3) {
  __shared__ float lA[64], lC[64];
  __shared__ float tile[64][65];
  int t = threadIdx.x;
  if (t < 64) {
    float s = 0.f, q = 0.f;
#pragma unroll
    for (int r = 0; r < NREP; ++r) { s += S3[r * 128 + t]; q += S3[r * 128 + 64 + t]; }
    float mean = s / CNT3;
    float var = q / CNT3 - mean * mean;
    float a = g3[t] * rsqrtf(var + EPSBN);
    lA[t] = a; lC[t] = be3[t] - mean * a;
  }
  __syncthreads();
  int blk = blockIdx.x;
  int b = blk >> 6, n0 = (blk & 63) << 6;
  int r = t >> 2, q = t & 3;
  const float4* hp = (const float4*)(h3 + (((size_t)((b << 12) + n0 + r)) << 6)) + q * 4;
#pragma unroll
  for (int ii = 0; ii < 4; ++ii) {
    float4 v = hp[ii];
    int c = q * 16 + ii * 4;
    tile[c + 0][r] = fmaxf(v.x * lA[c + 0] + lC[c + 0], 0.f);
    tile[c + 1][r] = fmaxf(v.y * lA[c + 1] + lC[c + 1], 0.f);
    tile[c + 2][r] = fmaxf(v.z * lA[c + 2] + lC[c + 2], 0.f);
    tile[c + 3][r] = fmaxf(v.w * lA[c + 3] + lC[c + 3], 0.f);
  }
  __syncthreads();
  int oo = t >> 2, seg = t & 3;
  float4* dst = (float4*)(out + (((size_t)(b * 64 + oo)) << 12) + n0 + seg * 16);
#pragma unroll
  for (int ii = 0; ii < 4; ++ii) {
    float4 v;
    v.x = tile[oo][seg * 16 + ii * 4 + 0];
    v.y = tile[oo][seg * 16 + ii * 4 + 1];
    v.z = tile[oo][seg * 16 + ii * 4 + 2];
    v.w = tile[oo][seg * 16 + ii * 4 + 3];
    dst[ii] = v;
  }
}

// ---------------------------------------------------------------------------
extern "C" void kernel_launch(void* const* d_in, const int* in_sizes, int n_in,
                              void* d_out, int out_size, void* d_ws, size_t ws_size,
                              hipStream_t stream) {
  const float* x = (const float*)d_in[0];
  const int* idx = (const int*)d_in[1];
  const float* W1 = (const float*)d_in[2];
  const float* g1 = (const float*)d_in[4];
  const float* be1 = (const float*)d_in[5];
  const float* W2 = (const float*)d_in[6];
  const float* g2 = (const float*)d_in[8];
  const float* be2 = (const float*)d_in[9];
  const float* W3 = (const float*)d_in[10];
  const float* g3 = (const float*)d_in[12];
  const float* be3 = (const float*)d_in[13];
  float* out = (float*)d_out;

  char* ws = (char*)d_ws;
  unsigned short* y   = (unsigned short*)ws;                 // 4 MB
  unsigned short* mnb = (unsigned short*)(ws + (4u << 20));  // 4 MB
  unsigned short* mxb = (unsigned short*)(ws + (8u << 20));  // 4 MB
  float* h3           = (float*)(ws + (12u << 20));          // 8 MB
  float* stats        = (float*)(ws + (20u << 20));          // 3*NREP*128 floats
  float* S1 = stats;
  float* S2 = stats + NREP * 128;
  float* S3 = stats + 2 * NREP * 128;

  k0_prep<<<512, 256, 0, stream>>>(x, W1, y, stats);
  k1_stats<<<1024, 256, 0, stream>>>(y, idx, S1);
  k2_main<<<1024, 256, 0, stream>>>(y, idx, W2, g1, be1, S1, mnb, mxb, S2);
  k3_gemm3<<<512, 256, 0, stream>>>(W3, mnb, mxb, g2, be2, S2, h3, S3);
  k4_out<<<512, 256, 0, stream>>>(h3, g3, be3, out, S3);
}

// Round 8
// 139.779 us; speedup vs baseline: 2.0275x; 1.0123x over previous
//
#include <hip/hip_runtime.h>

// Problem constants
#define EPSBN 1e-5f
#define CNT1 524288.0f   // B*N*K
#define CNT3 32768.0f    // B*N
#define NREP 16          // stats replicas (atomic spread)

typedef short v8s __attribute__((ext_vector_type(8)));
typedef float v16f __attribute__((ext_vector_type(16)));

__device__ __forceinline__ unsigned short f2bf(float f) {
  union { float f; unsigned u; } v; v.f = f;
  unsigned u = v.u;
  u += 0x7fffu + ((u >> 16) & 1u);   // RNE
  return (unsigned short)(u >> 16);
}
__device__ __forceinline__ unsigned pack2bf(float a, float b) {
  return (unsigned)f2bf(a) | ((unsigned)f2bf(b) << 16);
}
__device__ __forceinline__ float bflo(unsigned u) {
  union { unsigned u; float f; } v; v.u = u << 16; return v.f;
}
__device__ __forceinline__ float bfhi(unsigned u) {
  union { unsigned u; float f; } v; v.u = u & 0xffff0000u; return v.f;
}

// ---------------------------------------------------------------------------
// k0: y = W1*x (bf16, (B*N,64)); zero stats. 512 blocks.
// Block u -> batch u&7 (XCD-pinned, matches consumers), points (u>>3)*64.
// ---------------------------------------------------------------------------
__global__ __launch_bounds__(256) void k0_prep(
    const float* __restrict__ x, const float* __restrict__ W1f,
    unsigned short* __restrict__ y, float* __restrict__ stats) {
  __shared__ unsigned short ldsX[64 * 72];  // [point][ch], pad 72
  int blk = blockIdx.x, t = threadIdx.x;
  if (blk < 24) stats[blk * 256 + t] = 0.f;
  int b = blk & 7, n0 = (blk >> 3) << 6;
  int lane = t & 63, w = t >> 6;
#pragma unroll
  for (int i = 0; i < 16; ++i) {
    int c = w * 16 + i;
    ldsX[lane * 72 + c] = f2bf(x[(((size_t)(b * 64 + c)) << 12) + n0 + lane]);
  }
  __syncthreads();
  int l31 = lane & 31, lh = lane >> 5;
  int ot = w & 1, ph = w >> 1;
  int o = ot * 32 + l31;
  v16f acc;
#pragma unroll
  for (int i = 0; i < 16; ++i) acc[i] = 0.f;
#pragma unroll
  for (int ks = 0; ks < 4; ++ks) {
    const float* wrow = W1f + o * 64 + ks * 16 + lh * 8;
    float4 wa = *((const float4*)wrow);
    float4 wb = *((const float4*)(wrow + 4));
    v8s wf; unsigned* wu = (unsigned*)&wf;
    wu[0] = pack2bf(wa.x, wa.y); wu[1] = pack2bf(wa.z, wa.w);
    wu[2] = pack2bf(wb.x, wb.y); wu[3] = pack2bf(wb.z, wb.w);
    v8s af = *((const v8s*)&ldsX[(ph * 32 + l31) * 72 + ks * 16 + lh * 8]);
    acc = __builtin_amdgcn_mfma_f32_32x32x16_bf16(af, wf, acc, 0, 0, 0);
  }
#pragma unroll
  for (int i = 0; i < 16; ++i) {
    int row = (i & 3) + ((i >> 2) << 3) + (lh << 2);
    int pt = (b << 12) + n0 + ph * 32 + row;
    y[pt * 64 + o] = f2bf(acc[i]);
  }
}

// ---------------------------------------------------------------------------
// k1: stats1 = sum/sumsq of (y_j - y_i) over all edges. 1024 blocks.
// ---------------------------------------------------------------------------
__global__ __launch_bounds__(256) void k1_stats(
    const unsigned short* __restrict__ y, const int* __restrict__ idx,
    float* __restrict__ S1) {
  __shared__ float bs[64], bq[64];
  int t = threadIdx.x;
  if (t < 64) { bs[t] = 0.f; bq[t] = 0.f; }
  __syncthreads();
  int blk = blockIdx.x;
  int batch = blk & 7, bi = blk >> 3;       // bi 0..127
  int w = t >> 6, lane = t & 63;
  int ch = (lane & 7) << 3, eg = lane >> 3;
  int ebase = (batch << 16) + bi * 512 + w * 128;
  float ss[8], sq[8];
#pragma unroll
  for (int k = 0; k < 8; ++k) { ss[k] = 0.f; sq[k] = 0.f; }
  for (int it = 0; it < 16; ++it) {
    int p = ebase + it * 8 + eg;
    int j = idx[p];
    int site = p >> 4;
    uint4 uj = *((const uint4*)(y + (((size_t)((batch << 12) + j)) << 6) + ch));
    uint4 ui = *((const uint4*)(y + (((size_t)site) << 6) + ch));
    const unsigned* aj = (const unsigned*)&uj;
    const unsigned* ai = (const unsigned*)&ui;
#pragma unroll
    for (int d = 0; d < 4; ++d) {
      float d0 = bflo(aj[d]) - bflo(ai[d]);
      float d1 = bfhi(aj[d]) - bfhi(ai[d]);
      ss[2 * d] += d0; sq[2 * d] += d0 * d0;
      ss[2 * d + 1] += d1; sq[2 * d + 1] += d1 * d1;
    }
  }
#pragma unroll
  for (int k = 0; k < 8; ++k) {
    ss[k] += __shfl_xor(ss[k], 8);  sq[k] += __shfl_xor(sq[k], 8);
    ss[k] += __shfl_xor(ss[k], 16); sq[k] += __shfl_xor(sq[k], 16);
    ss[k] += __shfl_xor(ss[k], 32); sq[k] += __shfl_xor(sq[k], 32);
  }
  if (lane < 8) {
#pragma unroll
    for (int k = 0; k < 8; ++k) {
      atomicAdd(&bs[ch + k], ss[k]);
      atomicAdd(&bq[ch + k], sq[k]);
    }
  }
  __syncthreads();
  int rep = (blk >> 3) & (NREP - 1);
  if (t < 64) atomicAdd(&S1[rep * 128 + t], bs[t]);
  else if (t < 128) atomicAdd(&S1[rep * 128 + t], bq[t - 64]);
}

// ---------------------------------------------------------------------------
// k2: edge = relu(a1*(y_j - y_i) + c1) as MFMA A-frags, GEMM2, stats2,
// per-site min/max -> mnmx packed [site][mn:64|mx:64] bf16.
// 512 blocks x 4 waves x 8 tiles (round-4 shape).
// ---------------------------------------------------------------------------
__global__ __launch_bounds__(256) void k2_main(
    const unsigned short* __restrict__ y, const int* __restrict__ idx,
    const float* __restrict__ W2f,
    const float* __restrict__ g1, const float* __restrict__ be1,
    const float* __restrict__ S1,
    unsigned short* __restrict__ mnmx, float* __restrict__ S2) {
  __shared__ float bs[64], bq[64];
  __shared__ __align__(16) float lA[64];
  __shared__ __align__(16) float lC[64];
  int t = threadIdx.x;
  if (t < 64) {
    bs[t] = 0.f; bq[t] = 0.f;
    float s = 0.f, q = 0.f;
#pragma unroll
    for (int r = 0; r < NREP; ++r) { s += S1[r * 128 + t]; q += S1[r * 128 + 64 + t]; }
    float mean = s / CNT1;
    float var = q / CNT1 - mean * mean;
    float a = g1[t] * rsqrtf(var + EPSBN);
    lA[t] = a; lC[t] = be1[t] - mean * a;
  }
  __syncthreads();
  int blk = blockIdx.x;
  int batch = blk & 7, bi = blk >> 3;   // bi 0..63
  int w = t >> 6, lane = t & 63;
  int l31 = lane & 31, lh = lane >> 5;
  v8s w2[2][4];
#pragma unroll
  for (int s = 0; s < 2; ++s)
#pragma unroll
    for (int ks = 0; ks < 4; ++ks) {
      const float* wr = W2f + (s * 32 + l31) * 64 + ks * 16 + lh * 8;
      float4 wa = *((const float4*)wr);
      float4 wb = *((const float4*)(wr + 4));
      unsigned* wu = (unsigned*)&w2[s][ks];
      wu[0] = pack2bf(wa.x, wa.y); wu[1] = pack2bf(wa.z, wa.w);
      wu[2] = pack2bf(wb.x, wb.y); wu[3] = pack2bf(wb.z, wb.w);
    }
  float ss0 = 0.f, sq0 = 0.f, ss1 = 0.f, sq1 = 0.f;
  for (int it = 0; it < 8; ++it) {
    int tile = bi * 32 + w * 8 + it;            // 0..2047 within batch
    int p = (batch << 16) + (tile << 5) + l31;
    int j = idx[p];
    int site = p >> 4;
    const unsigned short* yj = y + (((size_t)((batch << 12) + j)) << 6) + lh * 8;
    const unsigned short* yi = y + (((size_t)site) << 6) + lh * 8;
    v16f b0, b1;
#pragma unroll
    for (int i = 0; i < 16; ++i) { b0[i] = 0.f; b1[i] = 0.f; }
#pragma unroll
    for (int ks = 0; ks < 4; ++ks) {
      uint4 uj = *((const uint4*)(yj + ks * 16));
      uint4 ui = *((const uint4*)(yi + ks * 16));
      float4 a0 = *((const float4*)&lA[ks * 16 + lh * 8]);
      float4 a1 = *((const float4*)&lA[ks * 16 + lh * 8 + 4]);
      float4 c0 = *((const float4*)&lC[ks * 16 + lh * 8]);
      float4 c1 = *((const float4*)&lC[ks * 16 + lh * 8 + 4]);
      float av[8] = {a0.x, a0.y, a0.z, a0.w, a1.x, a1.y, a1.z, a1.w};
      float cv[8] = {c0.x, c0.y, c0.z, c0.w, c1.x, c1.y, c1.z, c1.w};
      const unsigned* jw = (const unsigned*)&uj;
      const unsigned* iw = (const unsigned*)&ui;
      v8s af; unsigned* au = (unsigned*)&af;
#pragma unroll
      for (int d = 0; d < 4; ++d) {
        float e0 = fmaxf((bflo(jw[d]) - bflo(iw[d])) * av[2 * d] + cv[2 * d], 0.f);
        float e1 = fmaxf((bfhi(jw[d]) - bfhi(iw[d])) * av[2 * d + 1] + cv[2 * d + 1], 0.f);
        au[d] = pack2bf(e0, e1);
      }
      b0 = __builtin_amdgcn_mfma_f32_32x32x16_bf16(af, w2[0][ks], b0, 0, 0, 0);
      b1 = __builtin_amdgcn_mfma_f32_32x32x16_bf16(af, w2[1][ks], b1, 0, 0, 0);
    }
    float mx00 = b0[0], mn00 = b0[0], mx01 = b0[8], mn01 = b0[8];
    float mx10 = b1[0], mn10 = b1[0], mx11 = b1[8], mn11 = b1[8];
#pragma unroll
    for (int i = 0; i < 16; ++i) {
      ss0 += b0[i]; sq0 += b0[i] * b0[i];
      ss1 += b1[i]; sq1 += b1[i] * b1[i];
    }
#pragma unroll
    for (int i = 1; i < 8; ++i) {
      mx00 = fmaxf(mx00, b0[i]);     mn00 = fminf(mn00, b0[i]);
      mx01 = fmaxf(mx01, b0[8 + i]); mn01 = fminf(mn01, b0[8 + i]);
      mx10 = fmaxf(mx10, b1[i]);     mn10 = fminf(mn10, b1[i]);
      mx11 = fmaxf(mx11, b1[8 + i]); mn11 = fminf(mn11, b1[8 + i]);
    }
    mx00 = fmaxf(mx00, __shfl_xor(mx00, 32)); mn00 = fminf(mn00, __shfl_xor(mn00, 32));
    mx01 = fmaxf(mx01, __shfl_xor(mx01, 32)); mn01 = fminf(mn01, __shfl_xor(mn01, 32));
    mx10 = fmaxf(mx10, __shfl_xor(mx10, 32)); mn10 = fminf(mn10, __shfl_xor(mn10, 32));
    mx11 = fmaxf(mx11, __shfl_xor(mx11, 32)); mn11 = fminf(mn11, __shfl_xor(mn11, 32));
    int s2 = (batch << 12) + (tile << 1);
    if (lh == 0) {  // min halves
      mnmx[(size_t)(s2 + 0) * 128 + l31] = f2bf(mn00);
      mnmx[(size_t)(s2 + 1) * 128 + l31] = f2bf(mn01);
      mnmx[(size_t)(s2 + 0) * 128 + 32 + l31] = f2bf(mn10);
      mnmx[(size_t)(s2 + 1) * 128 + 32 + l31] = f2bf(mn11);
    } else {        // max halves
      mnmx[(size_t)(s2 + 0) * 128 + 64 + l31] = f2bf(mx00);
      mnmx[(size_t)(s2 + 1) * 128 + 64 + l31] = f2bf(mx01);
      mnmx[(size_t)(s2 + 0) * 128 + 96 + l31] = f2bf(mx10);
      mnmx[(size_t)(s2 + 1) * 128 + 96 + l31] = f2bf(mx11);
    }
  }
  ss0 += __shfl_xor(ss0, 32); sq0 += __shfl_xor(sq0, 32);
  ss1 += __shfl_xor(ss1, 32); sq1 += __shfl_xor(sq1, 32);
  if (lh == 0) {
    atomicAdd(&bs[l31], ss0); atomicAdd(&bq[l31], sq0);
    atomicAdd(&bs[32 + l31], ss1); atomicAdd(&bq[32 + l31], sq1);
  }
  __syncthreads();
  int rep = blk & (NREP - 1);
  if (t < 64) atomicAdd(&S2[rep * 128 + t], bs[t]);
  else if (t < 128) atomicAdd(&S2[rep * 128 + t], bq[t - 64]);
}

// ---------------------------------------------------------------------------
// k3: BN2 sign-select on packed min/max, ReLU, GEMM3 -> h3 bf16, stats3.
// 512 blocks; block u -> batch u&7 (matches k2's XCD pinning).
// ---------------------------------------------------------------------------
__global__ __launch_bounds__(256, 2) void k3_gemm3(
    const float* __restrict__ W3f, const unsigned short* __restrict__ mnmx,
    const float* __restrict__ g2, const float* __restrict__ be2,
    const float* __restrict__ S2, unsigned short* __restrict__ h3,
    float* __restrict__ S3) {
  __shared__ uint4 ldsA[64 * 9];
  __shared__ float bs[64], bq[64], lA[64], lC[64];
  int t = threadIdx.x;
  if (t < 64) {
    bs[t] = 0.f; bq[t] = 0.f;
    float s = 0.f, q = 0.f;
#pragma unroll
    for (int r = 0; r < NREP; ++r) { s += S2[r * 128 + t]; q += S2[r * 128 + 64 + t]; }
    float mean = s / CNT1;
    float var = q / CNT1 - mean * mean;
    float a = g2[t] * rsqrtf(var + EPSBN);
    lA[t] = a; lC[t] = be2[t] - mean * a;
  }
  __syncthreads();
  int lane = t & 63, wid = t >> 6;
  int rb = wid & 1, ctile = wid >> 1;
  int l31 = lane & 31, lh = lane >> 5;
  int o = ctile * 32 + l31;
  v8s wf[4];
#pragma unroll
  for (int ks = 0; ks < 4; ++ks) {
    const float* wr = W3f + o * 64 + ks * 16 + lh * 8;
    float4 wa = *((const float4*)wr);
    float4 wb = *((const float4*)(wr + 4));
    unsigned* wu = (unsigned*)&wf[ks];
    wu[0] = pack2bf(wa.x, wa.y); wu[1] = pack2bf(wa.z, wa.w);
    wu[2] = pack2bf(wb.x, wb.y); wu[3] = pack2bf(wb.z, wb.w);
  }
  int r = t >> 2, q = t & 3;
  int arow = rb * 32 + l31;
  int blk = blockIdx.x;
  int s0 = ((blk & 7) << 12) + ((blk >> 3) << 6);
  {
    int site = s0 + r;
    const uint4* mnp = (const uint4*)(mnmx + (size_t)site * 128 + q * 16);
    const uint4* mxp = (const uint4*)(mnmx + (size_t)site * 128 + 64 + q * 16);
    uint4 m0 = mnp[0], m1 = mnp[1], x0 = mxp[0], x1 = mxp[1];
    uint4 ch2[2];
    unsigned* cu = (unsigned*)ch2;
#pragma unroll
    for (int d = 0; d < 8; ++d) {
      unsigned md = (d < 4) ? ((const unsigned*)&m0)[d] : ((const unsigned*)&m1)[d - 4];
      unsigned xd = (d < 4) ? ((const unsigned*)&x0)[d] : ((const unsigned*)&x1)[d - 4];
      int c = q * 16 + 2 * d;
      float a0 = lA[c], a1 = lA[c + 1];
      float s0v = (a0 > 0.f) ? bflo(xd) : bflo(md);
      float s1v = (a1 > 0.f) ? bfhi(xd) : bfhi(md);
      float v0 = fmaxf(a0 * s0v + lC[c], 0.f);
      float v1 = fmaxf(a1 * s1v + lC[c + 1], 0.f);
      cu[d] = pack2bf(v0, v1);
    }
    ldsA[r * 9 + q * 2 + 0] = ch2[0];
    ldsA[r * 9 + q * 2 + 1] = ch2[1];
  }
  __syncthreads();
  v16f acc;
#pragma unroll
  for (int i = 0; i < 16; ++i) acc[i] = 0.f;
#pragma unroll
  for (int ks = 0; ks < 4; ++ks) {
    v8s a = *((const v8s*)&ldsA[arow * 9 + ks * 2 + lh]);
    acc = __builtin_amdgcn_mfma_f32_32x32x16_bf16(a, wf[ks], acc, 0, 0, 0);
  }
  float ssum = 0.f, ssq = 0.f;
#pragma unroll
  for (int i = 0; i < 16; ++i) {
    float vv = acc[i];
    ssum += vv; ssq += vv * vv;
    int row = (i & 3) + ((i >> 2) << 3) + (lh << 2);
    h3[(((size_t)(s0 + rb * 32 + row)) << 6) + o] = f2bf(vv);
  }
  ssum += __shfl_xor(ssum, 32);
  ssq += __shfl_xor(ssq, 32);
  if (lh == 0) { atomicAdd(&bs[o], ssum); atomicAdd(&bq[o], ssq); }
  __syncthreads();
  int rep = blk & (NREP - 1);
  if (t < 64) atomicAdd(&S3[rep * 128 + t], bs[t]);
  else if (t < 128) atomicAdd(&S3[rep * 128 + t], bq[t - 64]);
}

// ---------------------------------------------------------------------------
// k4: BN3+ReLU on bf16 h3, transpose (B,N,E)->(B,E,N), write out. 512 blocks.
// ---------------------------------------------------------------------------
__global__ void k4_out(const unsigned short* __restrict__ h3,
                       const float* __restrict__ g3, const float* __restrict__ be3,
                       float* __restrict__ out, const float* __restrict__ S3) {
  __shared__ float lA[64], lC[64];
  __shared__ float tile[64][65];
  int t = threadIdx.x;
  if (t < 64) {
    float s = 0.f, q = 0.f;
#pragma unroll
    for (int r = 0; r < NREP; ++r) { s += S3[r * 128 + t]; q += S3[r * 128 + 64 + t]; }
    float mean = s / CNT3;
    float var = q / CNT3 - mean * mean;
    float a = g3[t] * rsqrtf(var + EPSBN);
    lA[t] = a; lC[t] = be3[t] - mean * a;
  }
  __syncthreads();
  int blk = blockIdx.x;
  int b = blk >> 6, n0 = (blk & 63) << 6;
  int r = t >> 2, q = t & 3;
  const uint4* hp = (const uint4*)(h3 + (((size_t)((b << 12) + n0 + r)) << 6) + q * 16);
  uint4 h0 = hp[0], h1 = hp[1];
#pragma unroll
  for (int d = 0; d < 8; ++d) {
    unsigned hd = (d < 4) ? ((const unsigned*)&h0)[d] : ((const unsigned*)&h1)[d - 4];
    int c = q * 16 + 2 * d;
    tile[c + 0][r] = fmaxf(bflo(hd) * lA[c + 0] + lC[c + 0], 0.f);
    tile[c + 1][r] = fmaxf(bfhi(hd) * lA[c + 1] + lC[c + 1], 0.f);
  }
  __syncthreads();
  int oo = t >> 2, seg = t & 3;
  float4* dst = (float4*)(out + (((size_t)(b * 64 + oo)) << 12) + n0 + seg * 16);
#pragma unroll
  for (int ii = 0; ii < 4; ++ii) {
    float4 v;
    v.x = tile[oo][seg * 16 + ii * 4 + 0];
    v.y = tile[oo][seg * 16 + ii * 4 + 1];
    v.z = tile[oo][seg * 16 + ii * 4 + 2];
    v.w = tile[oo][seg * 16 + ii * 4 + 3];
    dst[ii] = v;
  }
}

// ---------------------------------------------------------------------------
extern "C" void kernel_launch(void* const* d_in, const int* in_sizes, int n_in,
                              void* d_out, int out_size, void* d_ws, size_t ws_size,
                              hipStream_t stream) {
  const float* x = (const float*)d_in[0];
  const int* idx = (const int*)d_in[1];
  const float* W1 = (const float*)d_in[2];
  const float* g1 = (const float*)d_in[4];
  const float* be1 = (const float*)d_in[5];
  const float* W2 = (const float*)d_in[6];
  const float* g2 = (const float*)d_in[8];
  const float* be2 = (const float*)d_in[9];
  const float* W3 = (const float*)d_in[10];
  const float* g3 = (const float*)d_in[12];
  const float* be3 = (const float*)d_in[13];
  float* out = (float*)d_out;

  char* ws = (char*)d_ws;
  unsigned short* y    = (unsigned short*)ws;                 // 4 MB
  unsigned short* mnmx = (unsigned short*)(ws + (4u << 20));  // 8 MB packed
  unsigned short* h3   = (unsigned short*)(ws + (12u << 20)); // 4 MB bf16
  float* stats         = (float*)(ws + (16u << 20));          // 3*NREP*128 floats
  float* S1 = stats;
  float* S2 = stats + NREP * 128;
  float* S3 = stats + 2 * NREP * 128;

  k0_prep<<<512, 256, 0, stream>>>(x, W1, y, stats);
  k1_stats<<<1024, 256, 0, stream>>>(y, idx, S1);
  k2_main<<<512, 256, 0, stream>>>(y, idx, W2, g1, be1, S1, mnmx, S2);
  k3_gemm3<<<512, 256, 0, stream>>>(W3, mnmx, g2, be2, S2, h3, S3);
  k4_out<<<512, 256, 0, stream>>>(h3, g3, be3, out, S3);
}